// Round 2
// baseline (258.416 us; speedup 1.0000x reference)
//
#include <hip/hip_runtime.h>
#include <hip/hip_cooperative_groups.h>

namespace cg = cooperative_groups;

// ws float layout
#define OFF_PART_U   0            // 256 blocks * 1024 h partials
#define OFF_PART_SY  262144       // 256 per-block y-sum partials
#define OFF_S        262400       // 8192: S0[4096] | S1[4096]
#define OFF_W2R      270592       // 1024
#define OFF_C        271616       // 1

__device__ __forceinline__ float tanh_fast(float x) {
    float e = __expf(x + x);
    return 1.0f - 2.0f * __builtin_amdgcn_rcpf(e + 1.0f);
}

union SharedU {
    struct { float qL[32][3]; float yL[32]; } a;                       // phase A
    struct { float uRed[8][32]; float syL; } b;                        // phase B
    struct { float S0L[4096]; float S1T[64*65]; float rhsL[4096]; } cd;// 49.4 KB
    struct { float4 WL[1024]; float w2rL[1024]; } e;                   // 20 KB
};

__global__ __launch_bounds__(256, 1) void fused(
    const float* __restrict__ input,
    const float* __restrict__ eqp,
    const float* __restrict__ qx0, const float* __restrict__ qx1,
    const float* __restrict__ Wx1, const float* __restrict__ bx1,
    const float* __restrict__ Wx2, const float* __restrict__ bx2,
    const float* __restrict__ Wq0a, const float* __restrict__ bq0a,
    const float* __restrict__ Wq0b, const float* __restrict__ bq0b,
    const float* __restrict__ Wq1a, const float* __restrict__ bq1a,
    const float* __restrict__ Wq1b, const float* __restrict__ bq1b,
    float* __restrict__ ws, float* __restrict__ out, int N, int NQ)
{
    cg::grid_group grid = cg::this_grid();
    __shared__ SharedU sh;
    const int b = blockIdx.x, tid = threadIdx.x;
    const int s = b >> 7, chunk = b & 127;

    // ---- phase 0: zero the S accumulator (atomic target in phase B)
    if (tid < 32) ws[OFF_S + b * 32 + tid] = 0.0f;

    // ---- phase A: u-partial over this block's 32 quad points (no atomics)
    {
        const int PPB = NQ / 128;                 // 32
        const float* qx = s ? qx1 : qx0;
        const float* Wa = s ? Wq1a : Wq0a;
        const float* ba = s ? bq1a : bq0a;
        float eq = eqp[0];
        float my_y = 0.0f;
        if (tid < PPB) {
            int a = chunk * PPB + tid;
            float q0 = qx[a*3+0], q1 = qx[a*3+1], q2 = qx[a*3+2];
            sh.a.qL[tid][0] = q0; sh.a.qL[tid][1] = q1; sh.a.qL[tid][2] = q2;
            my_y = __expf(-eq * (q0*q0 + q1*q1 + q2*q2));
            sh.a.yL[tid] = my_y;
        }
        __syncthreads();
        float w0[4], w1[4], w2[4], bb4[4], acc[4];
        #pragma unroll
        for (int k = 0; k < 4; ++k) {
            int h = tid + 256*k;
            w0[k] = Wa[h]; w1[k] = Wa[1024+h]; w2[k] = Wa[2048+h];
            bb4[k] = ba[h]; acc[k] = 0.0f;
        }
        for (int a = 0; a < PPB; ++a) {
            float q0 = sh.a.qL[a][0], q1 = sh.a.qL[a][1], q2 = sh.a.qL[a][2];
            float ya = sh.a.yL[a];
            #pragma unroll
            for (int k = 0; k < 4; ++k) {
                float z = fmaf(q0, w0[k], fmaf(q1, w1[k], fmaf(q2, w2[k], bb4[k])));
                acc[k] = fmaf(ya, tanh_fast(z), acc[k]);
            }
        }
        #pragma unroll
        for (int k = 0; k < 4; ++k)
            ws[OFF_PART_U + b*1024 + tid + 256*k] = acc[k];
        if (tid < 32) {
            float v = my_y;
            #pragma unroll
            for (int off = 16; off > 0; off >>= 1) v += __shfl_down(v, off);
            if (tid == 0) ws[OFF_PART_SY + b] = v;
        }
    }

    grid.sync();

    // ---- phase B: S_s[j] = sum_h u_s[h]*Wb[h,j] + sy_s*bb[j]  (the 32 MB read)
    {
        int r = b & 127, hc = r >> 2, jc = r & 3;
        const float* Wb = s ? Wq1b : Wq0b;
        const float* bb = s ? bq1b : bq0b;
        // reduce u over the 128 partials for h in [hc*32, hc*32+32)
        int hl = tid & 31, pg = tid >> 5;
        float accu = 0.0f;
        #pragma unroll 4
        for (int p = pg*16; p < pg*16 + 16; ++p)
            accu += ws[OFF_PART_U + (s*128 + p)*1024 + hc*32 + hl];
        sh.b.uRed[pg][hl] = accu;
        float sv = 0.0f;
        if (tid < 64)
            sv = ws[OFF_PART_SY + s*128 + tid] + ws[OFF_PART_SY + s*128 + 64 + tid];
        __syncthreads();
        if (tid < 32) {
            float t = 0.0f;
            #pragma unroll
            for (int g = 0; g < 8; ++g) t += sh.b.uRed[g][tid];
            sh.b.uRed[0][tid] = t;
        }
        if (tid < 64) {
            #pragma unroll
            for (int off = 32; off > 0; off >>= 1) sv += __shfl_down(sv, off);
            if (tid == 0) sh.b.syL = sv;
        }
        __syncthreads();
        float sy = sh.b.syL;
        int j = jc * 1024 + tid * 4;
        float4 acc;
        if (hc == 0) {
            float4 b4 = *reinterpret_cast<const float4*>(bb + j);
            acc = make_float4(sy*b4.x, sy*b4.y, sy*b4.z, sy*b4.w);
        } else {
            acc = make_float4(0.f, 0.f, 0.f, 0.f);
        }
        const float* row = Wb + (hc*32)*4096 + j;
        #pragma unroll 8
        for (int h = 0; h < 32; ++h) {
            float4 w = *reinterpret_cast<const float4*>(row);
            float uh = sh.b.uRed[0][h];
            acc.x = fmaf(uh, w.x, acc.x);
            acc.y = fmaf(uh, w.y, acc.y);
            acc.z = fmaf(uh, w.z, acc.z);
            acc.w = fmaf(uh, w.w, acc.w);
            row += 4096;
        }
        float* S = ws + OFF_S + s * 4096;
        atomicAdd(&S[j+0], acc.x);
        atomicAdd(&S[j+1], acc.y);
        atomicAdd(&S[j+2], acc.z);
        atomicAdd(&S[j+3], acc.w);
    }

    grid.sync();

    // ---- phase C+D: rhs = S0 @ S1^T (redundant per block, in LDS), then
    //      w2r[4b+w] = Wx2[4b+w,:] @ rhs ; block0/wave0 also c = bx2 @ rhs
    {
        const float* S = ws + OFF_S;
        for (int i = tid; i < 4096; i += 256) {
            sh.cd.S0L[i] = S[i];
            int d = i >> 6, x = i & 63;
            sh.cd.S1T[x*65 + d] = S[4096 + i];
        }
        __syncthreads();
        #pragma unroll
        for (int k = 0; k < 16; ++k) {
            int o = k*256 + tid;
            int br = o >> 6, d = o & 63;
            float acc = 0.0f;
            #pragma unroll 8
            for (int x = 0; x < 64; ++x)
                acc = fmaf(sh.cd.S0L[br*64 + x], sh.cd.S1T[x*65 + d], acc);
            sh.cd.rhsL[o] = acc;
        }
        __syncthreads();
        int wave = tid >> 6, lane = tid & 63;
        int rowIdx = b*4 + wave;                       // 0..1023
        const float4* rhs4 = reinterpret_cast<const float4*>(sh.cd.rhsL);
        {
            const float4* src4 = reinterpret_cast<const float4*>(Wx2 + rowIdx*4096);
            float acc = 0.0f;
            #pragma unroll
            for (int i = 0; i < 16; ++i) {
                float4 w  = src4[lane + 64*i];
                float4 rv = rhs4[lane + 64*i];
                acc += w.x*rv.x + w.y*rv.y + w.z*rv.z + w.w*rv.w;
            }
            #pragma unroll
            for (int off = 32; off > 0; off >>= 1) acc += __shfl_down(acc, off);
            if (lane == 0) ws[OFF_W2R + rowIdx] = acc;
        }
        if (b == 0 && wave == 0) {
            const float4* src4 = reinterpret_cast<const float4*>(bx2);
            float acc = 0.0f;
            #pragma unroll
            for (int i = 0; i < 16; ++i) {
                float4 w  = src4[lane + 64*i];
                float4 rv = rhs4[lane + 64*i];
                acc += w.x*rv.x + w.y*rv.y + w.z*rv.z + w.w*rv.w;
            }
            #pragma unroll
            for (int off = 32; off > 0; off >>= 1) acc += __shfl_down(acc, off);
            if (lane == 0) ws[OFF_C] = acc;
        }
    }

    grid.sync();

    // ---- phase E: out[n] = tanh(input[n]@Wx1 + bx1) @ w2r + c
    {
        #pragma unroll
        for (int k = 0; k < 4; ++k) {
            int h = tid + 256*k;
            sh.e.WL[h] = make_float4(Wx1[h], Wx1[1024+h], Wx1[2048+h], bx1[h]);
            sh.e.w2rL[h] = ws[OFF_W2R + h];
        }
        __syncthreads();
        float c = ws[OFF_C];
        int p = tid & 3;
        for (int n = b*64 + (tid >> 2); n < N; n += 256*64) {
            float in0 = input[n*3+0], in1 = input[n*3+1], in2 = input[n*3+2];
            float acc = 0.0f;
            #pragma unroll 4
            for (int i = 0; i < 256; ++i) {
                int h = 4*i + p;
                float4 w = sh.e.WL[h];
                float z = fmaf(in0, w.x, fmaf(in1, w.y, fmaf(in2, w.z, w.w)));
                acc = fmaf(tanh_fast(z), sh.e.w2rL[h], acc);
            }
            acc += __shfl_xor(acc, 1);
            acc += __shfl_xor(acc, 2);
            if (p == 0) out[n] = acc + c;
        }
    }
}

extern "C" void kernel_launch(void* const* d_in, const int* in_sizes, int n_in,
                              void* d_out, int out_size, void* d_ws, size_t ws_size,
                              hipStream_t stream)
{
    const float* input = (const float*)d_in[0];
    const float* eqp   = (const float*)d_in[1];
    const float* qx0   = (const float*)d_in[2];
    const float* qx1   = (const float*)d_in[3];
    const float* Wx1   = (const float*)d_in[4];
    const float* bx1   = (const float*)d_in[5];
    const float* Wx2   = (const float*)d_in[6];
    const float* bx2   = (const float*)d_in[7];
    const float* Wq0a  = (const float*)d_in[8];
    const float* bq0a  = (const float*)d_in[9];
    const float* Wq0b  = (const float*)d_in[10];
    const float* bq0b  = (const float*)d_in[11];
    const float* Wq1a  = (const float*)d_in[12];
    const float* bq1a  = (const float*)d_in[13];
    const float* Wq1b  = (const float*)d_in[14];
    const float* bq1b  = (const float*)d_in[15];
    float* ws  = (float*)d_ws;
    float* out = (float*)d_out;

    int N  = in_sizes[0] / 3;
    int NQ = in_sizes[2] / 3;

    void* args[] = {
        (void*)&input, (void*)&eqp, (void*)&qx0, (void*)&qx1,
        (void*)&Wx1, (void*)&bx1, (void*)&Wx2, (void*)&bx2,
        (void*)&Wq0a, (void*)&bq0a, (void*)&Wq0b, (void*)&bq0b,
        (void*)&Wq1a, (void*)&bq1a, (void*)&Wq1b, (void*)&bq1b,
        (void*)&ws, (void*)&out, (void*)&N, (void*)&NQ
    };
    hipLaunchCooperativeKernel((void*)fused, dim3(256), dim3(256), args, 0, stream);
}

// Round 3
// 137.848 us; speedup vs baseline: 1.8746x; 1.8746x over previous
//
#include <hip/hip_runtime.h>

// ws float layout
#define OFF_PART_U   0            // 256 blocks * 1024 h partials
#define OFF_PART_SY  262144       // 256 per-block y-sum partials
#define OFF_S        262400       // 8192: S0[4096] | S1[4096]
#define OFF_RHS      270592       // 4096
#define OFF_W2R      274688       // 1024
#define OFF_C        275712       // 1

__device__ __forceinline__ float tanh_fast(float x) {
    // tanh(x) = 1 - 2/(exp2(x*2*log2e)+1); exp2 direct saves a mul vs __expf(2x)
    float e = __builtin_amdgcn_exp2f(x * 2.885390081777927f);
    return 1.0f - 2.0f * __builtin_amdgcn_rcpf(e + 1.0f);
}

// K1: per-block partials of u_s[h] = sum_a y*tanh(qx@Wa+ba)[h], sy partial,
//     and zero the S accumulator (atomic target of K2).
// grid = 256 (128 blocks/set, 32 quad points each), 256 thr.
__global__ __launch_bounds__(256) void k1(
    const float* __restrict__ qx0, const float* __restrict__ qx1,
    const float* __restrict__ Wa0, const float* __restrict__ Wa1,
    const float* __restrict__ ba0, const float* __restrict__ ba1,
    const float* __restrict__ eqp, float* __restrict__ ws, int NQ)
{
    const int b = blockIdx.x, tid = threadIdx.x;
    const int s = b >> 7, chunk = b & 127;
    const int PPB = NQ / 128;                 // 32
    const float* qx = s ? qx1 : qx0;
    const float* Wa = s ? Wa1 : Wa0;
    const float* ba = s ? ba1 : ba0;

    __shared__ float qL[32][3];
    __shared__ float yL[32];

    if (tid < 32) ws[OFF_S + b*32 + tid] = 0.0f;   // zero S (consumed by K2)

    float eq = eqp[0];
    float my_y = 0.0f;
    if (tid < PPB) {
        int a = chunk * PPB + tid;
        float q0 = qx[a*3+0], q1 = qx[a*3+1], q2 = qx[a*3+2];
        qL[tid][0] = q0; qL[tid][1] = q1; qL[tid][2] = q2;
        my_y = __expf(-eq * (q0*q0 + q1*q1 + q2*q2));
        yL[tid] = my_y;
    }
    __syncthreads();

    float w0[4], w1[4], w2[4], bb4[4], acc[4];
    #pragma unroll
    for (int k = 0; k < 4; ++k) {
        int h = tid + 256*k;
        w0[k] = Wa[h]; w1[k] = Wa[1024+h]; w2[k] = Wa[2048+h];
        bb4[k] = ba[h]; acc[k] = 0.0f;
    }
    for (int a = 0; a < PPB; ++a) {
        float q0 = qL[a][0], q1 = qL[a][1], q2 = qL[a][2];  // LDS broadcast
        float ya = yL[a];
        #pragma unroll
        for (int k = 0; k < 4; ++k) {
            float z = fmaf(q0, w0[k], fmaf(q1, w1[k], fmaf(q2, w2[k], bb4[k])));
            acc[k] = fmaf(ya, tanh_fast(z), acc[k]);
        }
    }
    #pragma unroll
    for (int k = 0; k < 4; ++k)
        ws[OFF_PART_U + b*1024 + tid + 256*k] = acc[k];

    if (tid < 32) {
        float v = my_y;
        #pragma unroll
        for (int off = 16; off > 0; off >>= 1) v += __shfl_down(v, off);
        if (tid == 0) ws[OFF_PART_SY + b] = v;
    }
}

// K2: reduce u partials, then S_s[j] = sum_h u_s[h]*Wb[h,j] + sy_s*bb[j].
// grid = 256: s=bx>>7; hc=(bx&127)>>2 (32 h-chunks of 32); jc=bx&3 (4 j-chunks of 1024)
__global__ __launch_bounds__(256) void k2(
    const float* __restrict__ Wb0, const float* __restrict__ Wb1,
    const float* __restrict__ bb0, const float* __restrict__ bb1,
    float* __restrict__ ws)
{
    const int bx = blockIdx.x, tid = threadIdx.x;
    const int s = bx >> 7, r = bx & 127;
    const int hc = r >> 2, jc = r & 3;
    const float* Wb = s ? Wb1 : Wb0;
    const float* bb = s ? bb1 : bb0;

    __shared__ float uRed[8][32];
    __shared__ float syL;

    int hl = tid & 31, pg = tid >> 5;
    float accu = 0.0f;
    #pragma unroll 4
    for (int p = pg*16; p < pg*16 + 16; ++p)
        accu += ws[OFF_PART_U + (s*128 + p)*1024 + hc*32 + hl];
    uRed[pg][hl] = accu;
    float sv = 0.0f;
    if (tid < 64)
        sv = ws[OFF_PART_SY + s*128 + tid] + ws[OFF_PART_SY + s*128 + 64 + tid];
    __syncthreads();
    if (tid < 32) {
        float t = 0.0f;
        #pragma unroll
        for (int g = 0; g < 8; ++g) t += uRed[g][tid];
        uRed[0][tid] = t;
    }
    if (tid < 64) {
        #pragma unroll
        for (int off = 32; off > 0; off >>= 1) sv += __shfl_down(sv, off);
        if (tid == 0) syL = sv;
    }
    __syncthreads();

    float sy = syL;
    int j = jc * 1024 + tid * 4;
    float4 acc;
    if (hc == 0) {
        float4 b4 = *reinterpret_cast<const float4*>(bb + j);
        acc = make_float4(sy*b4.x, sy*b4.y, sy*b4.z, sy*b4.w);
    } else {
        acc = make_float4(0.f, 0.f, 0.f, 0.f);
    }
    const float* row = Wb + (hc*32)*4096 + j;
    #pragma unroll 8
    for (int h = 0; h < 32; ++h) {
        float4 w = *reinterpret_cast<const float4*>(row);
        float uh = uRed[0][h];
        acc.x = fmaf(uh, w.x, acc.x);
        acc.y = fmaf(uh, w.y, acc.y);
        acc.z = fmaf(uh, w.z, acc.z);
        acc.w = fmaf(uh, w.w, acc.w);
        row += 4096;
    }
    float* S = ws + OFF_S + s * 4096;
    atomicAdd(&S[j+0], acc.x);
    atomicAdd(&S[j+1], acc.y);
    atomicAdd(&S[j+2], acc.z);
    atomicAdd(&S[j+3], acc.w);
}

// K3: rhs[b*64+d] = sum_x S0[b,x]*S1[d,x].  grid = 16, 1 output/thread.
__global__ __launch_bounds__(256) void k3(float* __restrict__ ws)
{
    __shared__ float S0L[4096];
    __shared__ float S1T[64 * 65];
    const float* S0 = ws + OFF_S;
    const float* S1 = ws + OFF_S + 4096;
    float* rhs = ws + OFF_RHS;
    int tid = threadIdx.x;
    for (int i = tid; i < 4096; i += 256) {
        S0L[i] = S0[i];
        int d = i >> 6, x = i & 63;
        S1T[x * 65 + d] = S1[i];
    }
    __syncthreads();
    int o = blockIdx.x * 256 + tid;
    int b = o >> 6, d = o & 63;
    float acc = 0.0f;
    #pragma unroll 8
    for (int x = 0; x < 64; ++x)
        acc = fmaf(S0L[b*64 + x], S1T[x*65 + d], acc);
    rhs[o] = acc;
}

// K4: w2r[h] = Wx2[h,:]@rhs, c = bx2@rhs.  1 wave/row, grid = 257.
__global__ __launch_bounds__(256) void k4(
    const float* __restrict__ Wx2, const float* __restrict__ bx2,
    float* __restrict__ ws)
{
    __shared__ float4 rhsL[1024];
    const float4* rhs4 = reinterpret_cast<const float4*>(ws + OFF_RHS);
    int tid = threadIdx.x;
    for (int i = tid; i < 1024; i += 256) rhsL[i] = rhs4[i];
    __syncthreads();
    int wave = tid >> 6, lane = tid & 63;
    int rowIdx = blockIdx.x * 4 + wave;
    if (rowIdx > 1024) return;
    const float4* src4 = reinterpret_cast<const float4*>(
        (rowIdx < 1024) ? (Wx2 + rowIdx * 4096) : bx2);
    float acc = 0.0f;
    #pragma unroll
    for (int i = 0; i < 16; ++i) {
        float4 w  = src4[lane + 64*i];
        float4 rv = rhsL[lane + 64*i];
        acc += w.x*rv.x + w.y*rv.y + w.z*rv.z + w.w*rv.w;
    }
    #pragma unroll
    for (int off = 32; off > 0; off >>= 1) acc += __shfl_down(acc, off);
    if (lane == 0) {
        if (rowIdx < 1024) ws[OFF_W2R + rowIdx] = acc;
        else               ws[OFF_C] = acc;
    }
}

// K5: out[n] = tanh(input[n]@Wx1 + bx1) @ w2r + c.
// 32 rows/block, 8 lanes/row (h = 8*i + p), grid = N/32 = 512 (2 blocks/CU).
__global__ __launch_bounds__(256) void k5(
    const float* __restrict__ input, const float* __restrict__ Wx1,
    const float* __restrict__ bx1, const float* __restrict__ ws,
    float* __restrict__ out, int N)
{
    __shared__ float4 WL[1024];     // {Wx1[0,h], Wx1[1,h], Wx1[2,h], bx1[h]}
    __shared__ float w2rL[1024];
    int tid = threadIdx.x;
    #pragma unroll
    for (int k = 0; k < 4; ++k) {
        int h = tid + 256*k;
        WL[h] = make_float4(Wx1[h], Wx1[1024+h], Wx1[2048+h], bx1[h]);
        w2rL[h] = ws[OFF_W2R + h];
    }
    __syncthreads();
    float c = ws[OFF_C];
    int n = blockIdx.x * 32 + (tid >> 3);
    int p = tid & 7;
    int nc = (n < N) ? n : (N - 1);
    float in0 = input[nc*3+0], in1 = input[nc*3+1], in2 = input[nc*3+2];
    float acc = 0.0f;
    #pragma unroll 4
    for (int i = 0; i < 128; ++i) {
        int h = 8*i + p;
        float4 w = WL[h];
        float z = fmaf(in0, w.x, fmaf(in1, w.y, fmaf(in2, w.z, w.w)));
        acc = fmaf(tanh_fast(z), w2rL[h], acc);
    }
    acc += __shfl_xor(acc, 1);
    acc += __shfl_xor(acc, 2);
    acc += __shfl_xor(acc, 4);
    if (p == 0 && n < N) out[n] = acc + c;
}

extern "C" void kernel_launch(void* const* d_in, const int* in_sizes, int n_in,
                              void* d_out, int out_size, void* d_ws, size_t ws_size,
                              hipStream_t stream)
{
    const float* input = (const float*)d_in[0];
    const float* eqp   = (const float*)d_in[1];
    const float* qx0   = (const float*)d_in[2];
    const float* qx1   = (const float*)d_in[3];
    const float* Wx1   = (const float*)d_in[4];
    const float* bx1   = (const float*)d_in[5];
    const float* Wx2   = (const float*)d_in[6];
    const float* bx2   = (const float*)d_in[7];
    const float* Wq0a  = (const float*)d_in[8];
    const float* bq0a  = (const float*)d_in[9];
    const float* Wq0b  = (const float*)d_in[10];
    const float* bq0b  = (const float*)d_in[11];
    const float* Wq1a  = (const float*)d_in[12];
    const float* bq1a  = (const float*)d_in[13];
    const float* Wq1b  = (const float*)d_in[14];
    const float* bq1b  = (const float*)d_in[15];
    float* ws  = (float*)d_ws;
    float* out = (float*)d_out;

    int N  = in_sizes[0] / 3;
    int NQ = in_sizes[2] / 3;

    hipLaunchKernelGGL(k1, dim3(256), dim3(256), 0, stream,
                       qx0, qx1, Wq0a, Wq1a, bq0a, bq1a, eqp, ws, NQ);
    hipLaunchKernelGGL(k2, dim3(256), dim3(256), 0, stream,
                       Wq0b, Wq1b, bq0b, bq1b, ws);
    hipLaunchKernelGGL(k3, dim3(16), dim3(256), 0, stream, ws);
    hipLaunchKernelGGL(k4, dim3(257), dim3(256), 0, stream, Wx2, bx2, ws);
    hipLaunchKernelGGL(k5, dim3((N + 31) / 32), dim3(256), 0, stream,
                       input, Wx1, bx1, ws, out, N);
}